// Round 16
// baseline (207.839 us; speedup 1.0000x reference)
//
#include <hip/hip_runtime.h>

// Round 16: revert to round-13 split structure (132.1us best; fusion abandoned
// — rope_scatter is already HBM-optimal and the fused epilogue cost more than
// the saved round-trip). ONE change: flash gets amdgpu_waves_per_eu(6,6) —
// LDS (51200B) caps residency at 3 blocks/CU = 6 waves/EU, so the compiler's
// 64-VGPR / 8-wave target only causes spills (r13: WRITE 16.4MB vs 8.2MB out).
// 6-wave target => 85-VGPR budget => no spills, same occupancy.
// ws layout (bytes):
//   0        xb (8388608)            -> reused as qb after gemm1
//   8388608  wqb (6291456)
//   14680064 wob (2097152)
//   16777216 qkv (25165824)          -> first 8 MB reused as ob after rope
//   41943040 kb (8388608)
//   50331648 vT (8388608)

typedef float f32x4 __attribute__((ext_vector_type(4)));
typedef float fvec4 __attribute__((ext_vector_type(4)));
typedef __bf16 bf16x8 __attribute__((ext_vector_type(8)));
typedef unsigned int u32x4 __attribute__((ext_vector_type(4)));

#define S_SZ 2048
#define NH 16
#define DK 64

static __device__ __forceinline__ unsigned short f2bf(float f) {
  unsigned int u = __builtin_bit_cast(unsigned int, f);
  u += 0x7fffu + ((u >> 16) & 1u);
  return (unsigned short)(u >> 16);
}
static __device__ __forceinline__ float bf2f(unsigned short h) {
  unsigned int u = ((unsigned int)h) << 16;
  return __builtin_bit_cast(float, u);
}
static __device__ __forceinline__ unsigned int pk2(float a, float b) {
  return (unsigned int)f2bf(a) | ((unsigned int)f2bf(b) << 16);
}
static __device__ __forceinline__ bf16x8 ld16g(const unsigned short* p) {
  return __builtin_bit_cast(bf16x8, *(const u32x4*)p);
}
static __device__ __forceinline__ void gload_lds16(const unsigned short* g,
                                                   unsigned short* l) {
  __builtin_amdgcn_global_load_lds(
      (const __attribute__((address_space(1))) void*)g,
      (__attribute__((address_space(3))) void*)l, 16, 0, 0);
}
// raw v_exp_f32 = exp2
static __device__ __forceinline__ float ex2(float x) {
  float r;
  asm("v_exp_f32 %0, %1" : "=v"(r) : "v"(x));
  return r;
}

template <int CTRL>
static __device__ __forceinline__ float dppmov(float x) {
  return __builtin_bit_cast(
      float, __builtin_amdgcn_update_dpp(0, __builtin_bit_cast(int, x), CTRL,
                                         0xF, 0xF, true));
}
static __device__ __forceinline__ float rmax16(float x) {
  x = fmaxf(x, dppmov<0xB1>(x));   // quad_perm(1,0,3,2)
  x = fmaxf(x, dppmov<0x4E>(x));   // quad_perm(2,3,0,1)
  x = fmaxf(x, dppmov<0x141>(x));  // row_half_mirror
  x = fmaxf(x, dppmov<0x140>(x));  // row_mirror
  return x;
}
static __device__ __forceinline__ float rsum16(float x) {
  x += dppmov<0xB1>(x);
  x += dppmov<0x4E>(x);
  x += dppmov<0x141>(x);
  x += dppmov<0x140>(x);
  return x;
}

// ---------------- convert fp32 -> bf16 (x, w_qkv, w_out) ----------------
__global__ __launch_bounds__(256) void cvt_bf16(
    const float* __restrict__ x, const float* __restrict__ wq,
    const float* __restrict__ wo, unsigned short* __restrict__ xb,
    unsigned short* __restrict__ wqb, unsigned short* __restrict__ wob) {
  const int u = blockIdx.x * 256 + threadIdx.x;
  const float* src;
  unsigned short* dst;
  int idx;
  if (u < 524288) { src = x; dst = xb; idx = u; }
  else if (u < 917504) { src = wq; dst = wqb; idx = u - 524288; }
  else { src = wo; dst = wob; idx = u - 917504; }
  const fvec4* p = (const fvec4*)(src + (size_t)idx * 8);
  const fvec4 f0 = p[0], f1 = p[1];
  u32x4 o;
  o[0] = pk2(f0[0], f0[1]); o[1] = pk2(f0[2], f0[3]);
  o[2] = pk2(f1[0], f1[1]); o[3] = pk2(f1[2], f1[3]);
  *(u32x4*)(dst + (size_t)idx * 8) = o;
}

// ---------------- m97-style bf16 GEMM + XCD swizzle ----------------
template <bool OBF16>
__global__ __launch_bounds__(256) void gemm_bf16(
    const unsigned short* __restrict__ A, const unsigned short* __restrict__ B,
    const float* __restrict__ bias, void* __restrict__ Cp, int N, int K) {
  __shared__ unsigned short As[2][4096];
  __shared__ unsigned short Bs[2][4096];
  const int t = threadIdx.x;
  const int lane = t & 63, w = t >> 6;
  const int lo = lane & 15, g = lane >> 4;
  const int wr = (w >> 1) * 64, wc = (w & 1) * 64;
  const int gx = gridDim.x;
  int o = blockIdx.y * gx + blockIdx.x;
  const int nwg = gx * gridDim.y;
  o = (o & 7) * (nwg >> 3) + (o >> 3);
  const int by = o / gx, bx = o - by * gx;
  const int bRow = by * 128, bCol = bx * 128;
  const unsigned short* ap = A + (size_t)(bRow + (t >> 2)) * K + (t & 3) * 8;
  const unsigned short* bp = B + (size_t)(bCol + (t >> 2)) * K + (t & 3) * 8;
  const size_t rK = (size_t)64 * K;
  const int wb = w * 512;
  f32x4 acc[4][4] = {};
  gload_lds16(ap, As[0] + wb);
  gload_lds16(ap + rK, As[0] + 2048 + wb);
  gload_lds16(bp, Bs[0] + wb);
  gload_lds16(bp + rK, Bs[0] + 2048 + wb);
  const int nk = K >> 5;
  for (int kt = 0; kt < nk; ++kt) {
    __syncthreads();
    if (kt + 1 < nk) {
      const int k0 = (kt + 1) << 5;
      const int nb = (kt + 1) & 1;
      gload_lds16(ap + k0, As[nb] + wb);
      gload_lds16(ap + rK + k0, As[nb] + 2048 + wb);
      gload_lds16(bp + k0, Bs[nb] + wb);
      gload_lds16(bp + rK + k0, Bs[nb] + 2048 + wb);
    }
    const unsigned short* Ac = As[kt & 1];
    const unsigned short* Bc = Bs[kt & 1];
    bf16x8 aF[4], bF[4];
#pragma unroll
    for (int m = 0; m < 4; ++m) aF[m] = ld16g(Ac + (wr + m * 16 + lo) * 32 + 8 * g);
#pragma unroll
    for (int n = 0; n < 4; ++n) bF[n] = ld16g(Bc + (wc + n * 16 + lo) * 32 + 8 * g);
    __builtin_amdgcn_s_setprio(1);
#pragma unroll
    for (int m = 0; m < 4; ++m)
#pragma unroll
      for (int n = 0; n < 4; ++n)
        acc[m][n] = __builtin_amdgcn_mfma_f32_16x16x32_bf16(aF[m], bF[n], acc[m][n], 0, 0, 0);
    __builtin_amdgcn_s_setprio(0);
  }
#pragma unroll
  for (int m = 0; m < 4; ++m) {
#pragma unroll
    for (int n = 0; n < 4; ++n) {
      const int col = bCol + wc + n * 16 + lo;
      const float bv = bias[col];
#pragma unroll
      for (int r = 0; r < 4; ++r) {
        const int row = bRow + wr + m * 16 + g * 4 + r;
        const float v = acc[m][n][r] + bv;
        if constexpr (OBF16)
          ((unsigned short*)Cp)[(size_t)row * N + col] = f2bf(v);
        else
          ((float*)Cp)[(size_t)row * N + col] = v;
      }
    }
  }
}

// ------- rope + scatter (Q pre-scaled by 0.125*log2e for exp2 softmax) -------
__global__ __launch_bounds__(256) void rope_scatter(
    const unsigned short* __restrict__ qkv, unsigned short* __restrict__ Qo,
    unsigned short* __restrict__ Ko, unsigned short* __restrict__ Vt) {
  const int t = blockIdx.x * 256 + threadIdx.x;
  const int i = t & 31;
  const int s = (t >> 5) & (S_SZ - 1);
  const int h = (t >> 16) & (NH - 1);
  const int b = t >> 20;
  const unsigned short* row = qkv + (size_t)(b * S_SZ + s) * 3072;
  const float inv = exp2f((float)i * (-13.287712379549449f / 32.0f));
  const float ang = (float)s * inv;
  float sn, cs;
  sincosf(ang, &sn, &cs);
  const unsigned int qp = *(const unsigned int*)(row + h * 64 + 2 * i);
  const unsigned int kp = *(const unsigned int*)(row + 1024 + h * 64 + 2 * i);
  const unsigned int vp = *(const unsigned int*)(row + 2048 + h * 64 + 2 * i);
  const float qe = bf2f((unsigned short)qp), qo = bf2f((unsigned short)(qp >> 16));
  const float ke = bf2f((unsigned short)kp), ko = bf2f((unsigned short)(kp >> 16));
  const size_t hb = (size_t)(b * NH + h);
  const size_t qkbase = (hb * S_SZ + s) * DK + 2 * i;
  const float qs = 0.18033688011112042f;  // 0.125 * log2(e)
  *(unsigned int*)(Qo + qkbase) =
      pk2((qe * cs - qo * sn) * qs, (qe * sn + qo * cs) * qs);
  *(unsigned int*)(Ko + qkbase) = pk2(ke * cs - ko * sn, ke * sn + ko * cs);
  const size_t vb = (hb * DK + 2 * i) * S_SZ + s;
  Vt[vb] = (unsigned short)vp;
  Vt[vb + S_SZ] = (unsigned short)(vp >> 16);
}

// ---------------- flash attention (round-13 + waves_per_eu(6,6)) ----------
static __device__ __forceinline__ void stage8(const unsigned short* __restrict__ gbase,
                                              int gstride, unsigned short* tile, int t) {
  const int r = t >> 3;
  const int s16 = (t & 7) ^ (r & 7);
  gload_lds16(gbase + (size_t)r * gstride + (s16 << 3), tile + (t >> 6) * 512);
}

static __device__ __forceinline__ void attn_step(
    const unsigned short* __restrict__ Kl, const unsigned short* __restrict__ Vl,
    unsigned short* __restrict__ Pw, const bf16x8 aQ0, const bf16x8 aQ1,
    const bool diag, const int wq, const int lo, const int g,
    float* __restrict__ m, float* __restrict__ lsum, f32x4* __restrict__ oacc) {
  f32x4 s[4];
  __builtin_amdgcn_s_setprio(1);
#pragma unroll
  for (int c = 0; c < 4; ++c) {
    const int kr = c * 16 + lo;
    const int sw = kr & 7;
    const bf16x8 b0 =
        __builtin_bit_cast(bf16x8, *(const u32x4*)&Kl[kr * 64 + ((g ^ sw) << 3)]);
    const bf16x8 b1 =
        __builtin_bit_cast(bf16x8, *(const u32x4*)&Kl[kr * 64 + (((4 + g) ^ sw) << 3)]);
    f32x4 z = {};
    z = __builtin_amdgcn_mfma_f32_16x16x32_bf16(aQ0, b0, z, 0, 0, 0);
    z = __builtin_amdgcn_mfma_f32_16x16x32_bf16(aQ1, b1, z, 0, 0, 0);
    s[c] = z;
  }
  __builtin_amdgcn_s_setprio(0);
  if (diag) {
#pragma unroll
    for (int c = 0; c < 4; ++c)
#pragma unroll
      for (int r = 0; r < 4; ++r)
        if ((c * 16 + lo) > (wq * 16 + g * 4 + r)) s[c][r] = -__builtin_inff();
  }
#pragma unroll
  for (int r = 0; r < 4; ++r) {
    float rm = fmaxf(fmaxf(s[0][r], s[1][r]), fmaxf(s[2][r], s[3][r]));
    rm = rmax16(rm);
    const float mn = fmaxf(m[r], rm);
    const float alpha = ex2(m[r] - mn);
    m[r] = mn;
    float rs = 0.f;
#pragma unroll
    for (int c = 0; c < 4; ++c) {
      const float p = ex2(s[c][r] - mn);
      s[c][r] = p;
      rs += p;
    }
    rs = rsum16(rs);
    lsum[r] = lsum[r] * alpha + rs;
#pragma unroll
    for (int nt = 0; nt < 4; ++nt) oacc[nt][r] *= alpha;
#pragma unroll
    for (int c = 0; c < 4; ++c) Pw[(g * 4 + r) * 72 + c * 16 + lo] = f2bf(s[c][r]);
  }
  __builtin_amdgcn_s_setprio(1);
#pragma unroll
  for (int kc = 0; kc < 2; ++kc) {
    const bf16x8 aP =
        __builtin_bit_cast(bf16x8, *(const u32x4*)&Pw[lo * 72 + kc * 32 + 8 * g]);
#pragma unroll
    for (int nt = 0; nt < 4; ++nt) {
      const int d = nt * 16 + lo;
      const bf16x8 bV = __builtin_bit_cast(
          bf16x8, *(const u32x4*)&Vl[d * 64 + (((kc * 4 + g) ^ (d & 7)) << 3)]);
      oacc[nt] = __builtin_amdgcn_mfma_f32_16x16x32_bf16(aP, bV, oacc[nt], 0, 0, 0);
    }
  }
  __builtin_amdgcn_s_setprio(0);
}

// Block -> (j, bh) via XCD-clustering remap: XCD x owns heads 4x..4x+3.
//  waves 4-7 (side1): q-block qb=31-j, K-tiles 0..15      (16 steps)
//  waves 0-3 (side0): q-block qa=j tiles 0..qa, then qb tiles 16..qb (17 steps)
// LDS 51200B caps at 3 blocks/CU = 6 waves/EU; target exactly that so the
// register allocator gets the full 85-VGPR budget (no spills).
__global__
__attribute__((amdgpu_flat_work_group_size(512, 512), amdgpu_waves_per_eu(6, 6)))
void flash_attn(
    const unsigned short* __restrict__ Q, const unsigned short* __restrict__ K,
    const unsigned short* __restrict__ VT, unsigned short* __restrict__ O) {
  __shared__ unsigned short Kb[2][4096];
  __shared__ unsigned short Vb[2][4096];
  __shared__ unsigned short Pl[8][1152];
  const int t = threadIdx.x;
  const int lane = t & 63, w = t >> 6;
  const int lo = lane & 15, g = lane >> 4;
  const int flat = blockIdx.y * 16 + blockIdx.x;
  const int bh = ((flat & 7) << 2) | ((flat >> 3) & 3);
  const int j = flat >> 5;
  const int qa = j, qb = 31 - j;
  const unsigned short* Qh = Q + (size_t)bh * S_SZ * DK;
  const unsigned short* Kh = K + (size_t)bh * S_SZ * DK;
  const unsigned short* Vh = VT + (size_t)bh * DK * S_SZ;

  const int wq = w & 3;
  const bool s1 = w >= 4;
  const int rowMain = (s1 ? qb : qa) * 64 + wq * 16;
  const int rowB = qb * 64 + wq * 16;
  const bf16x8 aQ0 = ld16g(Qh + (size_t)(rowMain + lo) * DK + 8 * g);
  const bf16x8 aQ1 = ld16g(Qh + (size_t)(rowMain + lo) * DK + 32 + 8 * g);
  bf16x8 aQB0, aQB1;  // loaded lazily at phase-B transition (side0 only)

  float mA[4], lA[4], mB[4], lB[4];
  f32x4 oA[4] = {}, oB[4];
#pragma unroll
  for (int r = 0; r < 4; ++r) {
    mA[r] = -__builtin_inff();
    lA[r] = 0.f;
  }
  unsigned short* Pw = &Pl[w][0];

  for (int i = 0; i <= 16; ++i) {
    if (i < 16) {  // shared stream tile i into slot1
      stage8(Kh + (size_t)i * 64 * DK, DK, Kb[1], t);
      stage8(Vh + i * 64, S_SZ, Vb[1], t);
    }
    if (i > qa) {  // divergent stream tile 15+i-qa into slot0
      const int t0c = 15 + i - qa;
      stage8(Kh + (size_t)t0c * 64 * DK, DK, Kb[0], t);
      stage8(Vh + t0c * 64, S_SZ, Vb[0], t);
    }
    if (!s1 && i == qa + 1) {  // lazy phase-B state
      aQB0 = ld16g(Qh + (size_t)(rowB + lo) * DK + 8 * g);
      aQB1 = ld16g(Qh + (size_t)(rowB + lo) * DK + 32 + 8 * g);
#pragma unroll
      for (int r = 0; r < 4; ++r) {
        mB[r] = -__builtin_inff();
        lB[r] = 0.f;
      }
#pragma unroll
      for (int nt = 0; nt < 4; ++nt) oB[nt] = (f32x4){};
    }
    __syncthreads();
    if (s1) {
      if (i < 16) {
        attn_step(Kb[1], Vb[1], Pw, aQ0, aQ1, false, wq, lo, g, mA, lA, oA);
      } else {
        // publish partial (m,l,o) for merge; Kb[1]/Vb[1] dead at i=16
        float* ml = (float*)Pw;
#pragma unroll
        for (int r = 0; r < 4; ++r) {
          ml[r * 64 + lane] = mA[r];
          ml[(4 + r) * 64 + lane] = lA[r];
        }
        float* obase = (w < 6) ? ((float*)&Kb[1][0]) + (w - 4) * 1024
                               : ((float*)&Vb[1][0]) + (w - 6) * 1024;
#pragma unroll
        for (int nt = 0; nt < 4; ++nt)
#pragma unroll
          for (int r = 0; r < 4; ++r) obase[(nt * 4 + r) * 64 + lane] = oA[nt][r];
      }
    } else {
      if (i <= qa)
        attn_step(Kb[1], Vb[1], Pw, aQ0, aQ1, i == qa, wq, lo, g, mA, lA, oA);
      else
        attn_step(Kb[0], Vb[0], Pw, aQB0, aQB1, i == 16, wq, lo, g, mB, lB, oB);
    }
    __syncthreads();
  }

  if (!s1) {
    const int b = bh >> 4, h = bh & 15;
#pragma unroll
    for (int r = 0; r < 4; ++r) {
      const float inv = 1.0f / (lA[r] + 1e-8f);
      const size_t base = ((size_t)(b * S_SZ + rowMain + g * 4 + r)) * 1024 + h * DK;
#pragma unroll
      for (int nt = 0; nt < 4; ++nt) O[base + nt * 16 + lo] = f2bf(oA[nt][r] * inv);
    }
    const float* ml = (const float*)&Pl[w + 4][0];
    const float* obase = (w < 2) ? ((const float*)&Kb[1][0]) + w * 1024
                                 : ((const float*)&Vb[1][0]) + (w - 2) * 1024;
#pragma unroll
    for (int r = 0; r < 4; ++r) {
      const float m1 = ml[r * 64 + lane], l1 = ml[(4 + r) * 64 + lane];
      const float mh = fmaxf(mB[r], m1);
      const float a0 = ex2(mB[r] - mh), a1 = ex2(m1 - mh);
      const float linv = 1.0f / (lB[r] * a0 + l1 * a1 + 1e-8f);
      const size_t base = ((size_t)(b * S_SZ + rowB + g * 4 + r)) * 1024 + h * DK;
#pragma unroll
      for (int nt = 0; nt < 4; ++nt)
        O[base + nt * 16 + lo] =
            f2bf((oB[nt][r] * a0 + obase[(nt * 4 + r) * 64 + lane] * a1) * linv);
    }
  }
}

extern "C" void kernel_launch(void* const* d_in, const int* in_sizes, int n_in,
                              void* d_out, int out_size, void* d_ws, size_t ws_size,
                              hipStream_t stream) {
  const float* x = (const float*)d_in[0];
  const float* w_qkv = (const float*)d_in[1];
  const float* b_qkv = (const float*)d_in[2];
  const float* w_out = (const float*)d_in[3];
  const float* b_out = (const float*)d_in[4];
  float* out = (float*)d_out;

  char* ws = (char*)d_ws;
  unsigned short* xb = (unsigned short*)(ws);
  unsigned short* wqb = (unsigned short*)(ws + 8388608);
  unsigned short* wob = (unsigned short*)(ws + 14680064);
  unsigned short* qkv = (unsigned short*)(ws + 16777216);
  unsigned short* kb = (unsigned short*)(ws + 41943040);
  unsigned short* vt = (unsigned short*)(ws + 50331648);
  unsigned short* qb = xb;
  unsigned short* ob = qkv;

  cvt_bf16<<<4096, 256, 0, stream>>>(x, w_qkv, w_out, xb, wqb, wob);
  {
    dim3 grid(3072 / 128, 4096 / 128);
    gemm_bf16<true><<<grid, 256, 0, stream>>>(xb, wqb, b_qkv, qkv, 3072, 1024);
  }
  rope_scatter<<<(2 * NH * S_SZ * 32) / 256, 256, 0, stream>>>(qkv, qb, kb, vt);
  {
    dim3 grid(16, 2 * NH);
    flash_attn<<<grid, 512, 0, stream>>>(qb, kb, vt, ob);
  }
  {
    dim3 grid(1024 / 128, 4096 / 128);
    gemm_bf16<false><<<grid, 256, 0, stream>>>(ob, wob, b_out, out, 1024, 1024);
  }
}

// Round 17
// 131.678 us; speedup vs baseline: 1.5784x; 1.5784x over previous
//
#include <hip/hip_runtime.h>

// Round 17: exact restore of round-13 (best measured: 132.07us).
//  - waves_per_eu experiment (r16) reverted: compiler gave VGPR 40 + 267MB
//    spills, flash 135us. Occupancy attributes on this toolchain are
//    unpredictable; r13's 64-VGPR/8MB-spill point is the accepted floor.
//  - Pipeline: cvt_bf16 -> gemm_bf16<bf16 out> -> rope_scatter -> flash_attn
//    (balanced pair-split, DPP reduce, exp2 softmax, lazy phase-B)
//    -> gemm_bf16<fp32 out>.
// ws layout (bytes):
//   0        xb (8388608)            -> reused as qb after gemm1
//   8388608  wqb (6291456)
//   14680064 wob (2097152)
//   16777216 qkv (25165824)          -> first 8 MB reused as ob after rope
//   41943040 kb (8388608)
//   50331648 vT (8388608)

typedef float f32x4 __attribute__((ext_vector_type(4)));
typedef float fvec4 __attribute__((ext_vector_type(4)));
typedef __bf16 bf16x8 __attribute__((ext_vector_type(8)));
typedef unsigned int u32x4 __attribute__((ext_vector_type(4)));

#define S_SZ 2048
#define NH 16
#define DK 64

static __device__ __forceinline__ unsigned short f2bf(float f) {
  unsigned int u = __builtin_bit_cast(unsigned int, f);
  u += 0x7fffu + ((u >> 16) & 1u);
  return (unsigned short)(u >> 16);
}
static __device__ __forceinline__ float bf2f(unsigned short h) {
  unsigned int u = ((unsigned int)h) << 16;
  return __builtin_bit_cast(float, u);
}
static __device__ __forceinline__ unsigned int pk2(float a, float b) {
  return (unsigned int)f2bf(a) | ((unsigned int)f2bf(b) << 16);
}
static __device__ __forceinline__ bf16x8 ld16g(const unsigned short* p) {
  return __builtin_bit_cast(bf16x8, *(const u32x4*)p);
}
static __device__ __forceinline__ void gload_lds16(const unsigned short* g,
                                                   unsigned short* l) {
  __builtin_amdgcn_global_load_lds(
      (const __attribute__((address_space(1))) void*)g,
      (__attribute__((address_space(3))) void*)l, 16, 0, 0);
}
// raw v_exp_f32 = exp2
static __device__ __forceinline__ float ex2(float x) {
  float r;
  asm("v_exp_f32 %0, %1" : "=v"(r) : "v"(x));
  return r;
}

template <int CTRL>
static __device__ __forceinline__ float dppmov(float x) {
  return __builtin_bit_cast(
      float, __builtin_amdgcn_update_dpp(0, __builtin_bit_cast(int, x), CTRL,
                                         0xF, 0xF, true));
}
static __device__ __forceinline__ float rmax16(float x) {
  x = fmaxf(x, dppmov<0xB1>(x));   // quad_perm(1,0,3,2)
  x = fmaxf(x, dppmov<0x4E>(x));   // quad_perm(2,3,0,1)
  x = fmaxf(x, dppmov<0x141>(x));  // row_half_mirror
  x = fmaxf(x, dppmov<0x140>(x));  // row_mirror
  return x;
}
static __device__ __forceinline__ float rsum16(float x) {
  x += dppmov<0xB1>(x);
  x += dppmov<0x4E>(x);
  x += dppmov<0x141>(x);
  x += dppmov<0x140>(x);
  return x;
}

// ---------------- convert fp32 -> bf16 (x, w_qkv, w_out) ----------------
__global__ __launch_bounds__(256) void cvt_bf16(
    const float* __restrict__ x, const float* __restrict__ wq,
    const float* __restrict__ wo, unsigned short* __restrict__ xb,
    unsigned short* __restrict__ wqb, unsigned short* __restrict__ wob) {
  const int u = blockIdx.x * 256 + threadIdx.x;
  const float* src;
  unsigned short* dst;
  int idx;
  if (u < 524288) { src = x; dst = xb; idx = u; }
  else if (u < 917504) { src = wq; dst = wqb; idx = u - 524288; }
  else { src = wo; dst = wob; idx = u - 917504; }
  const fvec4* p = (const fvec4*)(src + (size_t)idx * 8);
  const fvec4 f0 = p[0], f1 = p[1];
  u32x4 o;
  o[0] = pk2(f0[0], f0[1]); o[1] = pk2(f0[2], f0[3]);
  o[2] = pk2(f1[0], f1[1]); o[3] = pk2(f1[2], f1[3]);
  *(u32x4*)(dst + (size_t)idx * 8) = o;
}

// ---------------- m97-style bf16 GEMM + XCD swizzle ----------------
template <bool OBF16>
__global__ __launch_bounds__(256) void gemm_bf16(
    const unsigned short* __restrict__ A, const unsigned short* __restrict__ B,
    const float* __restrict__ bias, void* __restrict__ Cp, int N, int K) {
  __shared__ unsigned short As[2][4096];
  __shared__ unsigned short Bs[2][4096];
  const int t = threadIdx.x;
  const int lane = t & 63, w = t >> 6;
  const int lo = lane & 15, g = lane >> 4;
  const int wr = (w >> 1) * 64, wc = (w & 1) * 64;
  const int gx = gridDim.x;
  int o = blockIdx.y * gx + blockIdx.x;
  const int nwg = gx * gridDim.y;
  o = (o & 7) * (nwg >> 3) + (o >> 3);
  const int by = o / gx, bx = o - by * gx;
  const int bRow = by * 128, bCol = bx * 128;
  const unsigned short* ap = A + (size_t)(bRow + (t >> 2)) * K + (t & 3) * 8;
  const unsigned short* bp = B + (size_t)(bCol + (t >> 2)) * K + (t & 3) * 8;
  const size_t rK = (size_t)64 * K;
  const int wb = w * 512;
  f32x4 acc[4][4] = {};
  gload_lds16(ap, As[0] + wb);
  gload_lds16(ap + rK, As[0] + 2048 + wb);
  gload_lds16(bp, Bs[0] + wb);
  gload_lds16(bp + rK, Bs[0] + 2048 + wb);
  const int nk = K >> 5;
  for (int kt = 0; kt < nk; ++kt) {
    __syncthreads();
    if (kt + 1 < nk) {
      const int k0 = (kt + 1) << 5;
      const int nb = (kt + 1) & 1;
      gload_lds16(ap + k0, As[nb] + wb);
      gload_lds16(ap + rK + k0, As[nb] + 2048 + wb);
      gload_lds16(bp + k0, Bs[nb] + wb);
      gload_lds16(bp + rK + k0, Bs[nb] + 2048 + wb);
    }
    const unsigned short* Ac = As[kt & 1];
    const unsigned short* Bc = Bs[kt & 1];
    bf16x8 aF[4], bF[4];
#pragma unroll
    for (int m = 0; m < 4; ++m) aF[m] = ld16g(Ac + (wr + m * 16 + lo) * 32 + 8 * g);
#pragma unroll
    for (int n = 0; n < 4; ++n) bF[n] = ld16g(Bc + (wc + n * 16 + lo) * 32 + 8 * g);
    __builtin_amdgcn_s_setprio(1);
#pragma unroll
    for (int m = 0; m < 4; ++m)
#pragma unroll
      for (int n = 0; n < 4; ++n)
        acc[m][n] = __builtin_amdgcn_mfma_f32_16x16x32_bf16(aF[m], bF[n], acc[m][n], 0, 0, 0);
    __builtin_amdgcn_s_setprio(0);
  }
#pragma unroll
  for (int m = 0; m < 4; ++m) {
#pragma unroll
    for (int n = 0; n < 4; ++n) {
      const int col = bCol + wc + n * 16 + lo;
      const float bv = bias[col];
#pragma unroll
      for (int r = 0; r < 4; ++r) {
        const int row = bRow + wr + m * 16 + g * 4 + r;
        const float v = acc[m][n][r] + bv;
        if constexpr (OBF16)
          ((unsigned short*)Cp)[(size_t)row * N + col] = f2bf(v);
        else
          ((float*)Cp)[(size_t)row * N + col] = v;
      }
    }
  }
}

// ------- rope + scatter (Q pre-scaled by 0.125*log2e for exp2 softmax) -------
__global__ __launch_bounds__(256) void rope_scatter(
    const unsigned short* __restrict__ qkv, unsigned short* __restrict__ Qo,
    unsigned short* __restrict__ Ko, unsigned short* __restrict__ Vt) {
  const int t = blockIdx.x * 256 + threadIdx.x;
  const int i = t & 31;
  const int s = (t >> 5) & (S_SZ - 1);
  const int h = (t >> 16) & (NH - 1);
  const int b = t >> 20;
  const unsigned short* row = qkv + (size_t)(b * S_SZ + s) * 3072;
  const float inv = exp2f((float)i * (-13.287712379549449f / 32.0f));
  const float ang = (float)s * inv;
  float sn, cs;
  sincosf(ang, &sn, &cs);
  const unsigned int qp = *(const unsigned int*)(row + h * 64 + 2 * i);
  const unsigned int kp = *(const unsigned int*)(row + 1024 + h * 64 + 2 * i);
  const unsigned int vp = *(const unsigned int*)(row + 2048 + h * 64 + 2 * i);
  const float qe = bf2f((unsigned short)qp), qo = bf2f((unsigned short)(qp >> 16));
  const float ke = bf2f((unsigned short)kp), ko = bf2f((unsigned short)(kp >> 16));
  const size_t hb = (size_t)(b * NH + h);
  const size_t qkbase = (hb * S_SZ + s) * DK + 2 * i;
  const float qs = 0.18033688011112042f;  // 0.125 * log2(e)
  *(unsigned int*)(Qo + qkbase) =
      pk2((qe * cs - qo * sn) * qs, (qe * sn + qo * cs) * qs);
  *(unsigned int*)(Ko + qkbase) = pk2(ke * cs - ko * sn, ke * sn + ko * cs);
  const size_t vb = (hb * DK + 2 * i) * S_SZ + s;
  Vt[vb] = (unsigned short)vp;
  Vt[vb + S_SZ] = (unsigned short)(vp >> 16);
}

// ---------------- flash attention (round-13 exact) ----------------
static __device__ __forceinline__ void stage8(const unsigned short* __restrict__ gbase,
                                              int gstride, unsigned short* tile, int t) {
  const int r = t >> 3;
  const int s16 = (t & 7) ^ (r & 7);
  gload_lds16(gbase + (size_t)r * gstride + (s16 << 3), tile + (t >> 6) * 512);
}

static __device__ __forceinline__ void attn_step(
    const unsigned short* __restrict__ Kl, const unsigned short* __restrict__ Vl,
    unsigned short* __restrict__ Pw, const bf16x8 aQ0, const bf16x8 aQ1,
    const bool diag, const int wq, const int lo, const int g,
    float* __restrict__ m, float* __restrict__ lsum, f32x4* __restrict__ oacc) {
  f32x4 s[4];
  __builtin_amdgcn_s_setprio(1);
#pragma unroll
  for (int c = 0; c < 4; ++c) {
    const int kr = c * 16 + lo;
    const int sw = kr & 7;
    const bf16x8 b0 =
        __builtin_bit_cast(bf16x8, *(const u32x4*)&Kl[kr * 64 + ((g ^ sw) << 3)]);
    const bf16x8 b1 =
        __builtin_bit_cast(bf16x8, *(const u32x4*)&Kl[kr * 64 + (((4 + g) ^ sw) << 3)]);
    f32x4 z = {};
    z = __builtin_amdgcn_mfma_f32_16x16x32_bf16(aQ0, b0, z, 0, 0, 0);
    z = __builtin_amdgcn_mfma_f32_16x16x32_bf16(aQ1, b1, z, 0, 0, 0);
    s[c] = z;
  }
  __builtin_amdgcn_s_setprio(0);
  if (diag) {
#pragma unroll
    for (int c = 0; c < 4; ++c)
#pragma unroll
      for (int r = 0; r < 4; ++r)
        if ((c * 16 + lo) > (wq * 16 + g * 4 + r)) s[c][r] = -__builtin_inff();
  }
#pragma unroll
  for (int r = 0; r < 4; ++r) {
    float rm = fmaxf(fmaxf(s[0][r], s[1][r]), fmaxf(s[2][r], s[3][r]));
    rm = rmax16(rm);
    const float mn = fmaxf(m[r], rm);
    const float alpha = ex2(m[r] - mn);
    m[r] = mn;
    float rs = 0.f;
#pragma unroll
    for (int c = 0; c < 4; ++c) {
      const float p = ex2(s[c][r] - mn);
      s[c][r] = p;
      rs += p;
    }
    rs = rsum16(rs);
    lsum[r] = lsum[r] * alpha + rs;
#pragma unroll
    for (int nt = 0; nt < 4; ++nt) oacc[nt][r] *= alpha;
#pragma unroll
    for (int c = 0; c < 4; ++c) Pw[(g * 4 + r) * 72 + c * 16 + lo] = f2bf(s[c][r]);
  }
  __builtin_amdgcn_s_setprio(1);
#pragma unroll
  for (int kc = 0; kc < 2; ++kc) {
    const bf16x8 aP =
        __builtin_bit_cast(bf16x8, *(const u32x4*)&Pw[lo * 72 + kc * 32 + 8 * g]);
#pragma unroll
    for (int nt = 0; nt < 4; ++nt) {
      const int d = nt * 16 + lo;
      const bf16x8 bV = __builtin_bit_cast(
          bf16x8, *(const u32x4*)&Vl[d * 64 + (((kc * 4 + g) ^ (d & 7)) << 3)]);
      oacc[nt] = __builtin_amdgcn_mfma_f32_16x16x32_bf16(aP, bV, oacc[nt], 0, 0, 0);
    }
  }
  __builtin_amdgcn_s_setprio(0);
}

// Block -> (j, bh) via XCD-clustering remap: XCD x owns heads 4x..4x+3.
//  waves 4-7 (side1): q-block qb=31-j, K-tiles 0..15      (16 steps)
//  waves 0-3 (side0): q-block qa=j tiles 0..qa, then qb tiles 16..qb (17 steps)
__global__ __launch_bounds__(512, 4) void flash_attn(
    const unsigned short* __restrict__ Q, const unsigned short* __restrict__ K,
    const unsigned short* __restrict__ VT, unsigned short* __restrict__ O) {
  __shared__ unsigned short Kb[2][4096];
  __shared__ unsigned short Vb[2][4096];
  __shared__ unsigned short Pl[8][1152];
  const int t = threadIdx.x;
  const int lane = t & 63, w = t >> 6;
  const int lo = lane & 15, g = lane >> 4;
  const int flat = blockIdx.y * 16 + blockIdx.x;
  const int bh = ((flat & 7) << 2) | ((flat >> 3) & 3);
  const int j = flat >> 5;
  const int qa = j, qb = 31 - j;
  const unsigned short* Qh = Q + (size_t)bh * S_SZ * DK;
  const unsigned short* Kh = K + (size_t)bh * S_SZ * DK;
  const unsigned short* Vh = VT + (size_t)bh * DK * S_SZ;

  const int wq = w & 3;
  const bool s1 = w >= 4;
  const int rowMain = (s1 ? qb : qa) * 64 + wq * 16;
  const int rowB = qb * 64 + wq * 16;
  const bf16x8 aQ0 = ld16g(Qh + (size_t)(rowMain + lo) * DK + 8 * g);
  const bf16x8 aQ1 = ld16g(Qh + (size_t)(rowMain + lo) * DK + 32 + 8 * g);
  bf16x8 aQB0, aQB1;  // loaded lazily at phase-B transition (side0 only)

  float mA[4], lA[4], mB[4], lB[4];
  f32x4 oA[4] = {}, oB[4];
#pragma unroll
  for (int r = 0; r < 4; ++r) {
    mA[r] = -__builtin_inff();
    lA[r] = 0.f;
  }
  unsigned short* Pw = &Pl[w][0];

  for (int i = 0; i <= 16; ++i) {
    if (i < 16) {  // shared stream tile i into slot1
      stage8(Kh + (size_t)i * 64 * DK, DK, Kb[1], t);
      stage8(Vh + i * 64, S_SZ, Vb[1], t);
    }
    if (i > qa) {  // divergent stream tile 15+i-qa into slot0
      const int t0c = 15 + i - qa;
      stage8(Kh + (size_t)t0c * 64 * DK, DK, Kb[0], t);
      stage8(Vh + t0c * 64, S_SZ, Vb[0], t);
    }
    if (!s1 && i == qa + 1) {  // lazy phase-B state
      aQB0 = ld16g(Qh + (size_t)(rowB + lo) * DK + 8 * g);
      aQB1 = ld16g(Qh + (size_t)(rowB + lo) * DK + 32 + 8 * g);
#pragma unroll
      for (int r = 0; r < 4; ++r) {
        mB[r] = -__builtin_inff();
        lB[r] = 0.f;
      }
#pragma unroll
      for (int nt = 0; nt < 4; ++nt) oB[nt] = (f32x4){};
    }
    __syncthreads();
    if (s1) {
      if (i < 16) {
        attn_step(Kb[1], Vb[1], Pw, aQ0, aQ1, false, wq, lo, g, mA, lA, oA);
      } else {
        // publish partial (m,l,o) for merge; Kb[1]/Vb[1] dead at i=16
        float* ml = (float*)Pw;
#pragma unroll
        for (int r = 0; r < 4; ++r) {
          ml[r * 64 + lane] = mA[r];
          ml[(4 + r) * 64 + lane] = lA[r];
        }
        float* obase = (w < 6) ? ((float*)&Kb[1][0]) + (w - 4) * 1024
                               : ((float*)&Vb[1][0]) + (w - 6) * 1024;
#pragma unroll
        for (int nt = 0; nt < 4; ++nt)
#pragma unroll
          for (int r = 0; r < 4; ++r) obase[(nt * 4 + r) * 64 + lane] = oA[nt][r];
      }
    } else {
      if (i <= qa)
        attn_step(Kb[1], Vb[1], Pw, aQ0, aQ1, i == qa, wq, lo, g, mA, lA, oA);
      else
        attn_step(Kb[0], Vb[0], Pw, aQB0, aQB1, i == 16, wq, lo, g, mB, lB, oB);
    }
    __syncthreads();
  }

  if (!s1) {
    const int b = bh >> 4, h = bh & 15;
#pragma unroll
    for (int r = 0; r < 4; ++r) {
      const float inv = 1.0f / (lA[r] + 1e-8f);
      const size_t base = ((size_t)(b * S_SZ + rowMain + g * 4 + r)) * 1024 + h * DK;
#pragma unroll
      for (int nt = 0; nt < 4; ++nt) O[base + nt * 16 + lo] = f2bf(oA[nt][r] * inv);
    }
    const float* ml = (const float*)&Pl[w + 4][0];
    const float* obase = (w < 2) ? ((const float*)&Kb[1][0]) + w * 1024
                                 : ((const float*)&Vb[1][0]) + (w - 2) * 1024;
#pragma unroll
    for (int r = 0; r < 4; ++r) {
      const float m1 = ml[r * 64 + lane], l1 = ml[(4 + r) * 64 + lane];
      const float mh = fmaxf(mB[r], m1);
      const float a0 = ex2(mB[r] - mh), a1 = ex2(m1 - mh);
      const float linv = 1.0f / (lB[r] * a0 + l1 * a1 + 1e-8f);
      const size_t base = ((size_t)(b * S_SZ + rowB + g * 4 + r)) * 1024 + h * DK;
#pragma unroll
      for (int nt = 0; nt < 4; ++nt)
        O[base + nt * 16 + lo] =
            f2bf((oB[nt][r] * a0 + obase[(nt * 4 + r) * 64 + lane] * a1) * linv);
    }
  }
}

extern "C" void kernel_launch(void* const* d_in, const int* in_sizes, int n_in,
                              void* d_out, int out_size, void* d_ws, size_t ws_size,
                              hipStream_t stream) {
  const float* x = (const float*)d_in[0];
  const float* w_qkv = (const float*)d_in[1];
  const float* b_qkv = (const float*)d_in[2];
  const float* w_out = (const float*)d_in[3];
  const float* b_out = (const float*)d_in[4];
  float* out = (float*)d_out;

  char* ws = (char*)d_ws;
  unsigned short* xb = (unsigned short*)(ws);
  unsigned short* wqb = (unsigned short*)(ws + 8388608);
  unsigned short* wob = (unsigned short*)(ws + 14680064);
  unsigned short* qkv = (unsigned short*)(ws + 16777216);
  unsigned short* kb = (unsigned short*)(ws + 41943040);
  unsigned short* vt = (unsigned short*)(ws + 50331648);
  unsigned short* qb = xb;
  unsigned short* ob = qkv;

  cvt_bf16<<<4096, 256, 0, stream>>>(x, w_qkv, w_out, xb, wqb, wob);
  {
    dim3 grid(3072 / 128, 4096 / 128);
    gemm_bf16<true><<<grid, 256, 0, stream>>>(xb, wqb, b_qkv, qkv, 3072, 1024);
  }
  rope_scatter<<<(2 * NH * S_SZ * 32) / 256, 256, 0, stream>>>(qkv, qb, kb, vt);
  {
    dim3 grid(16, 2 * NH);
    flash_attn<<<grid, 512, 0, stream>>>(qb, kb, vt, ob);
  }
  {
    dim3 grid(1024 / 128, 4096 / 128);
    gemm_bf16<false><<<grid, 256, 0, stream>>>(ob, wob, b_out, out, 1024, 1024);
  }
}